// Round 1
// baseline (439.908 us; speedup 1.0000x reference)
//
#include <hip/hip_runtime.h>

#define D 128
#define C 5

// ---------------------------------------------------------------------------
// Kernel 1: precompute U = ufeat @ W1[:, :128].T  and V = ifeat @ W1[:, 128:].T
// Each block handles 32 rows. W1 half staged transposed in LDS (64 KB).
// 8 subgroups of 32 lanes; each thread: 4 rows x 4 outputs = 16 accumulators.
// ---------------------------------------------------------------------------
__global__ __launch_bounds__(256) void precompute_uv(
    const float* __restrict__ ufeat, const float* __restrict__ ifeat,
    const float* __restrict__ W1, float* __restrict__ U, float* __restrict__ V,
    int n_users, int n_movies, int groupsU)
{
    __shared__ float w1t[D * D];  // [k][j] transposed half of W1, 64 KB

    int gid = blockIdx.x;
    const float* feat;
    float* out;
    int off, base_row, nrows;
    if (gid < groupsU) {
        feat = ufeat; out = U; off = 0;
        base_row = gid * 32; nrows = n_users;
    } else {
        feat = ifeat; out = V; off = D;
        base_row = (gid - groupsU) * 32; nrows = n_movies;
    }

    int tid = threadIdx.x;
    // Stage W1 half transposed: w1t[k*128 + j] = W1[j*256 + off + k].
    // idx enumeration: j = idx&127 (lane-consecutive -> conflict-free LDS write),
    // k = idx>>7 (thread streams row j with stride 2 -> L1-friendly).
    for (int idx = tid; idx < D * D; idx += 256) {
        int j = idx & 127;
        int k = idx >> 7;
        w1t[k * D + j] = W1[j * (2 * D) + off + k];
    }
    __syncthreads();

    int sg = tid >> 5;   // subgroup 0..7
    int jj = tid & 31;   // output quad index: outputs 4*jj .. 4*jj+3
    int r0 = base_row + sg * 4;

    // Clamp row indices so loads are always in-bounds (stores stay guarded).
    int ri0 = (r0 + 0 < nrows) ? (r0 + 0) : (nrows - 1);
    int ri1 = (r0 + 1 < nrows) ? (r0 + 1) : (nrows - 1);
    int ri2 = (r0 + 2 < nrows) ? (r0 + 2) : (nrows - 1);
    int ri3 = (r0 + 3 < nrows) ? (r0 + 3) : (nrows - 1);
    const float* f0 = feat + (size_t)ri0 * D;
    const float* f1 = feat + (size_t)ri1 * D;
    const float* f2 = feat + (size_t)ri2 * D;
    const float* f3 = feat + (size_t)ri3 * D;

    float acc0[4] = {0.f, 0.f, 0.f, 0.f};
    float acc1[4] = {0.f, 0.f, 0.f, 0.f};
    float acc2[4] = {0.f, 0.f, 0.f, 0.f};
    float acc3[4] = {0.f, 0.f, 0.f, 0.f};

    #pragma unroll 4
    for (int k = 0; k < D; ++k) {
        float4 w = *reinterpret_cast<const float4*>(&w1t[k * D + jj * 4]);
        float a = f0[k];
        float b = f1[k];
        float c = f2[k];
        float d = f3[k];
        acc0[0] += a * w.x; acc0[1] += a * w.y; acc0[2] += a * w.z; acc0[3] += a * w.w;
        acc1[0] += b * w.x; acc1[1] += b * w.y; acc1[2] += b * w.z; acc1[3] += b * w.w;
        acc2[0] += c * w.x; acc2[1] += c * w.y; acc2[2] += c * w.z; acc2[3] += c * w.w;
        acc3[0] += d * w.x; acc3[1] += d * w.y; acc3[2] += d * w.z; acc3[3] += d * w.w;
    }

    if (r0 + 0 < nrows) {
        float4 v4 = {acc0[0], acc0[1], acc0[2], acc0[3]};
        *reinterpret_cast<float4*>(&out[(size_t)(r0 + 0) * D + jj * 4]) = v4;
    }
    if (r0 + 1 < nrows) {
        float4 v4 = {acc1[0], acc1[1], acc1[2], acc1[3]};
        *reinterpret_cast<float4*>(&out[(size_t)(r0 + 1) * D + jj * 4]) = v4;
    }
    if (r0 + 2 < nrows) {
        float4 v4 = {acc2[0], acc2[1], acc2[2], acc2[3]};
        *reinterpret_cast<float4*>(&out[(size_t)(r0 + 2) * D + jj * 4]) = v4;
    }
    if (r0 + 3 < nrows) {
        float4 v4 = {acc3[0], acc3[1], acc3[2], acc3[3]};
        *reinterpret_cast<float4*>(&out[(size_t)(r0 + 3) * D + jj * 4]) = v4;
    }
}

// ---------------------------------------------------------------------------
// Kernel 2: per-edge  score[e] = relu(U[src[e]] + V[dst[e]]) @ W2.T
// Block = 256 threads = 4 waves; each wave handles 16 edges.
// Phase A: cooperative gather+add+relu into padded LDS (pad 132).
// Phase B: lane = (edge, k-quarter); 5 accumulators; shfl_xor reduce over 4 lanes.
// ---------------------------------------------------------------------------
__global__ __launch_bounds__(256) void edge_mlp(
    const float* __restrict__ U, const float* __restrict__ V,
    const float* __restrict__ W2,
    const int* __restrict__ src, const int* __restrict__ dst,
    float* __restrict__ out, int E)
{
    __shared__ float w2s[C * D];          // 2560 B
    __shared__ float hbuf[4][16][132];    // 4 waves x 16 edges x (128+4 pad) = 33792 B

    int tid = threadIdx.x;
    for (int idx = tid; idx < C * D; idx += 256) w2s[idx] = W2[idx];
    __syncthreads();

    int w = tid >> 6;  // wave id
    int l = tid & 63;  // lane id
    int base = blockIdx.x * 64 + w * 16;

    // Phase A: h = relu(U[s] + V[d]) for 16 edges, float2 per lane
    #pragma unroll 4
    for (int i = 0; i < 16; ++i) {
        int e = base + i;
        if (e < E) {
            int s = src[e];
            int d = dst[e];
            float2 u2 = *reinterpret_cast<const float2*>(&U[(size_t)s * D + 2 * l]);
            float2 v2 = *reinterpret_cast<const float2*>(&V[(size_t)d * D + 2 * l]);
            float2 h2;
            h2.x = fmaxf(u2.x + v2.x, 0.0f);
            h2.y = fmaxf(u2.y + v2.y, 0.0f);
            *reinterpret_cast<float2*>(&hbuf[w][i][2 * l]) = h2;
        }
    }
    __syncthreads();

    // Phase B: lane l -> edge (l>>2), k-quarter (l&3); k = ks + 4*i
    int eloc = l >> 2;
    int ks = l & 3;
    float acc[C] = {0.f, 0.f, 0.f, 0.f, 0.f};
    const float* hrow = &hbuf[w][eloc][0];
    #pragma unroll 8
    for (int i = 0; i < 32; ++i) {
        int k = ks + 4 * i;
        float h = hrow[k];
        #pragma unroll
        for (int c = 0; c < C; ++c) acc[c] += h * w2s[c * D + k];
    }
    #pragma unroll
    for (int c = 0; c < C; ++c) {
        acc[c] += __shfl_xor(acc[c], 1);
        acc[c] += __shfl_xor(acc[c], 2);
    }
    int e = base + eloc;
    if (ks == 0 && e < E) {
        #pragma unroll
        for (int c = 0; c < C; ++c) out[(size_t)e * C + c] = acc[c];
    }
}

extern "C" void kernel_launch(void* const* d_in, const int* in_sizes, int n_in,
                              void* d_out, int out_size, void* d_ws, size_t ws_size,
                              hipStream_t stream) {
    (void)n_in; (void)out_size; (void)ws_size;
    const float* ufeat = (const float*)d_in[0];
    const float* ifeat = (const float*)d_in[1];
    const float* W1    = (const float*)d_in[2];
    const float* W2    = (const float*)d_in[3];
    const int*   src   = (const int*)d_in[4];
    const int*   dst   = (const int*)d_in[5];

    int n_users  = in_sizes[0] / D;
    int n_movies = in_sizes[1] / D;
    int E        = in_sizes[4];

    float* out = (float*)d_out;
    float* Ubuf = (float*)d_ws;                       // n_users * 128 floats
    float* Vbuf = Ubuf + (size_t)n_users * D;         // n_movies * 128 floats

    int groupsU = (n_users + 31) / 32;
    int groupsV = (n_movies + 31) / 32;
    precompute_uv<<<groupsU + groupsV, 256, 0, stream>>>(
        ufeat, ifeat, W1, Ubuf, Vbuf, n_users, n_movies, groupsU);

    int eblocks = (E + 63) / 64;
    edge_mlp<<<eblocks, 256, 0, stream>>>(Ubuf, Vbuf, W2, src, dst, out, E);
}

// Round 2
// 232.651 us; speedup vs baseline: 1.8908x; 1.8908x over previous
//
#include <hip/hip_runtime.h>

#define D 128
#define C 5

__device__ __forceinline__ unsigned short f2bf(float x) {
    unsigned int u = __float_as_uint(x);
    unsigned int r = (u + 0x7fffu + ((u >> 16) & 1u)) >> 16;
    return (unsigned short)r;
}

// ---------------------------------------------------------------------------
// Kernel 1: U = ufeat @ W1[:, :128].T ; V = ifeat @ W1[:, 128:].T  (bf16 out)
// Block = 256 threads, 64 rows x 128 outputs.
// LDS: feature tile 64x128 fp32 (32 KB, staged once, broadcast reads),
//      W1-half chunk 32k x 128 (16 KB, restaged 4x). Total 48 KB -> 3 blk/CU.
// Thread (sg=tid>>5, jj=tid&31): 8 rows x 4 cols = 32 accumulators.
// Inner loop: LDS float4 reads + FMA only — no global loads on critical path.
// ---------------------------------------------------------------------------
__global__ __launch_bounds__(256) void precompute_uv(
    const float* __restrict__ ufeat, const float* __restrict__ ifeat,
    const float* __restrict__ W1, unsigned short* __restrict__ U,
    unsigned short* __restrict__ V, int n_users, int n_movies, int groupsU)
{
    __shared__ float featS[64 * D];   // [row][k], 32 KB
    __shared__ float w1tS[32 * D];    // [k][j] chunk, 16 KB

    int gid = blockIdx.x;
    const float* feat;
    unsigned short* out;
    int off, base_row, nrows;
    if (gid < groupsU) {
        feat = ufeat; out = U; off = 0;
        base_row = gid * 64; nrows = n_users;
    } else {
        feat = ifeat; out = V; off = D;
        base_row = (gid - groupsU) * 64; nrows = n_movies;
    }

    int tid = threadIdx.x;

    // Stage feature tile: 2048 float4 slots, fully coalesced.
    for (int slot = tid; slot < (64 * D) / 4; slot += 256) {
        int row = slot >> 5;        // 32 float4 per row
        int k4  = slot & 31;
        int gr = base_row + row;
        if (gr >= nrows) gr = nrows - 1;   // clamp: loads in-bounds, stores guarded
        *reinterpret_cast<float4*>(&featS[row * D + k4 * 4]) =
            *reinterpret_cast<const float4*>(&feat[(size_t)gr * D + k4 * 4]);
    }

    int sg = tid >> 5;   // 0..7 -> rows sg*8 .. sg*8+7
    int jj = tid & 31;   // cols 4*jj .. 4*jj+3

    float acc[8][4];
    #pragma unroll
    for (int r = 0; r < 8; ++r)
        #pragma unroll
        for (int c = 0; c < 4; ++c) acc[r][c] = 0.f;

    for (int kc = 0; kc < 4; ++kc) {
        __syncthreads();   // (kc=0: featS ready; kc>0: w1tS reuse safe)
        // Stage W1 chunk transposed: w1tS[k][j] = W1[j][off + kc*32 + k].
        // Thread t: j = t>>1, 16 k's = 4 coalesced float4 row-loads; LDS
        // scatter writes are 2-way (free).
        {
            int j  = tid >> 1;
            int kh = (tid & 1) * 16;
            const float* wp = &W1[(size_t)j * (2 * D) + off + kc * 32 + kh];
            float4 a0 = *reinterpret_cast<const float4*>(&wp[0]);
            float4 a1 = *reinterpret_cast<const float4*>(&wp[4]);
            float4 a2 = *reinterpret_cast<const float4*>(&wp[8]);
            float4 a3 = *reinterpret_cast<const float4*>(&wp[12]);
            w1tS[(kh + 0) * D + j] = a0.x;  w1tS[(kh + 1) * D + j] = a0.y;
            w1tS[(kh + 2) * D + j] = a0.z;  w1tS[(kh + 3) * D + j] = a0.w;
            w1tS[(kh + 4) * D + j] = a1.x;  w1tS[(kh + 5) * D + j] = a1.y;
            w1tS[(kh + 6) * D + j] = a1.z;  w1tS[(kh + 7) * D + j] = a1.w;
            w1tS[(kh + 8) * D + j] = a2.x;  w1tS[(kh + 9) * D + j] = a2.y;
            w1tS[(kh + 10) * D + j] = a2.z; w1tS[(kh + 11) * D + j] = a2.w;
            w1tS[(kh + 12) * D + j] = a3.x; w1tS[(kh + 13) * D + j] = a3.y;
            w1tS[(kh + 14) * D + j] = a3.z; w1tS[(kh + 15) * D + j] = a3.w;
        }
        __syncthreads();

        #pragma unroll 2
        for (int k4 = 0; k4 < 8; ++k4) {
            float4 wv0 = *reinterpret_cast<float4*>(&w1tS[(k4 * 4 + 0) * D + jj * 4]);
            float4 wv1 = *reinterpret_cast<float4*>(&w1tS[(k4 * 4 + 1) * D + jj * 4]);
            float4 wv2 = *reinterpret_cast<float4*>(&w1tS[(k4 * 4 + 2) * D + jj * 4]);
            float4 wv3 = *reinterpret_cast<float4*>(&w1tS[(k4 * 4 + 3) * D + jj * 4]);
            #pragma unroll
            for (int r = 0; r < 8; ++r) {
                float4 fv = *reinterpret_cast<float4*>(
                    &featS[(sg * 8 + r) * D + kc * 32 + k4 * 4]);
                acc[r][0] += fv.x * wv0.x; acc[r][1] += fv.x * wv0.y;
                acc[r][2] += fv.x * wv0.z; acc[r][3] += fv.x * wv0.w;
                acc[r][0] += fv.y * wv1.x; acc[r][1] += fv.y * wv1.y;
                acc[r][2] += fv.y * wv1.z; acc[r][3] += fv.y * wv1.w;
                acc[r][0] += fv.z * wv2.x; acc[r][1] += fv.z * wv2.y;
                acc[r][2] += fv.z * wv2.z; acc[r][3] += fv.z * wv2.w;
                acc[r][0] += fv.w * wv3.x; acc[r][1] += fv.w * wv3.y;
                acc[r][2] += fv.w * wv3.z; acc[r][3] += fv.w * wv3.w;
            }
        }
    }

    // Store bf16, 8 B per row per thread (coalesced 256 B per subgroup-row).
    #pragma unroll
    for (int r = 0; r < 8; ++r) {
        int gr = base_row + sg * 8 + r;
        if (gr < nrows) {
            unsigned int lo = (unsigned int)f2bf(acc[r][0]) |
                              ((unsigned int)f2bf(acc[r][1]) << 16);
            unsigned int hi = (unsigned int)f2bf(acc[r][2]) |
                              ((unsigned int)f2bf(acc[r][3]) << 16);
            uint2 p; p.x = lo; p.y = hi;
            *reinterpret_cast<uint2*>(&out[(size_t)gr * D + jj * 4]) = p;
        }
    }
}

// ---------------------------------------------------------------------------
// Kernel 2: score[e] = relu(U[src[e]] + V[dst[e]]) @ W2.T   (U,V bf16)
// Block = 256 = 4 waves; wave handles 16 edges.
// Phase A: gather (4 B/lane/row) + add + relu -> padded LDS (132, 2-way free).
// Phase B: lane = (edge l>>2, k-quarter l&3); 5 acc; shfl_xor reduce over 4.
// ---------------------------------------------------------------------------
__global__ __launch_bounds__(256) void edge_mlp(
    const unsigned short* __restrict__ U, const unsigned short* __restrict__ V,
    const float* __restrict__ W2,
    const int* __restrict__ src, const int* __restrict__ dst,
    float* __restrict__ out, int E)
{
    __shared__ float w2s[C * D];          // 2560 B
    __shared__ float hbuf[4][16][132];    // 33792 B

    int tid = threadIdx.x;
    for (int idx = tid; idx < C * D; idx += 256) w2s[idx] = W2[idx];
    __syncthreads();

    int w = tid >> 6;
    int l = tid & 63;
    int base = blockIdx.x * 64 + w * 16;

    // One index load per lane; broadcast via shfl (lanes 0..15 authoritative).
    int i16 = base + (l & 15);
    int sv = 0, dv = 0;
    if (i16 < E) { sv = src[i16]; dv = dst[i16]; }

    #pragma unroll 4
    for (int i = 0; i < 16; ++i) {
        int e = base + i;
        if (e < E) {
            int s = __shfl(sv, i);
            int d = __shfl(dv, i);
            unsigned int uu = *reinterpret_cast<const unsigned int*>(&U[(size_t)s * D + 2 * l]);
            unsigned int vv = *reinterpret_cast<const unsigned int*>(&V[(size_t)d * D + 2 * l]);
            float ux = __uint_as_float((uu & 0xffffu) << 16);
            float uy = __uint_as_float(uu & 0xffff0000u);
            float vx = __uint_as_float((vv & 0xffffu) << 16);
            float vy = __uint_as_float(vv & 0xffff0000u);
            float2 h2;
            h2.x = fmaxf(ux + vx, 0.f);
            h2.y = fmaxf(uy + vy, 0.f);
            *reinterpret_cast<float2*>(&hbuf[w][i][2 * l]) = h2;
        }
    }
    __syncthreads();

    int eloc = l >> 2;
    int ks = l & 3;
    float acc[C] = {0.f, 0.f, 0.f, 0.f, 0.f};
    const float* hrow = &hbuf[w][eloc][0];
    #pragma unroll 8
    for (int i = 0; i < 32; ++i) {
        int k = ks + 4 * i;
        float h = hrow[k];
        #pragma unroll
        for (int c = 0; c < C; ++c) acc[c] += h * w2s[c * D + k];
    }
    #pragma unroll
    for (int c = 0; c < C; ++c) {
        acc[c] += __shfl_xor(acc[c], 1);
        acc[c] += __shfl_xor(acc[c], 2);
    }
    int e = base + eloc;
    if (ks == 0 && e < E) {
        #pragma unroll
        for (int c = 0; c < C; ++c) out[(size_t)e * C + c] = acc[c];
    }
}

extern "C" void kernel_launch(void* const* d_in, const int* in_sizes, int n_in,
                              void* d_out, int out_size, void* d_ws, size_t ws_size,
                              hipStream_t stream) {
    (void)n_in; (void)out_size; (void)ws_size;
    const float* ufeat = (const float*)d_in[0];
    const float* ifeat = (const float*)d_in[1];
    const float* W1    = (const float*)d_in[2];
    const float* W2    = (const float*)d_in[3];
    const int*   src   = (const int*)d_in[4];
    const int*   dst   = (const int*)d_in[5];

    int n_users  = in_sizes[0] / D;
    int n_movies = in_sizes[1] / D;
    int E        = in_sizes[4];

    float* out = (float*)d_out;
    unsigned short* Ubuf = (unsigned short*)d_ws;          // n_users*128 bf16
    unsigned short* Vbuf = Ubuf + (size_t)n_users * D;     // n_movies*128 bf16

    int groupsU = (n_users + 63) / 64;
    int groupsV = (n_movies + 63) / 64;
    precompute_uv<<<groupsU + groupsV, 256, 0, stream>>>(
        ufeat, ifeat, W1, Ubuf, Vbuf, n_users, n_movies, groupsU);

    int eblocks = (E + 63) / 64;
    edge_mlp<<<eblocks, 256, 0, stream>>>(Ubuf, Vbuf, W2, src, dst, out, E);
}

// Round 3
// 163.091 us; speedup vs baseline: 2.6973x; 1.4265x over previous
//
#include <hip/hip_runtime.h>
#include <hip/hip_fp16.h>

#define D 128
#define C 5

typedef _Float16 half8 __attribute__((ext_vector_type(8)));
typedef float f32x4 __attribute__((ext_vector_type(4)));

// ---------------------------------------------------------------------------
// Kernel 1: U = ufeat @ W1[:, :128].T ; V = ifeat @ W1[:, 128:].T  (fp16 out)
// Block = 256 threads, 64 rows x 128 outputs. fp32 compute in LDS tiles.
// ---------------------------------------------------------------------------
__global__ __launch_bounds__(256) void precompute_uv(
    const float* __restrict__ ufeat, const float* __restrict__ ifeat,
    const float* __restrict__ W1, _Float16* __restrict__ U,
    _Float16* __restrict__ V, int n_users, int n_movies, int groupsU)
{
    __shared__ float featS[64 * D];   // 32 KB
    __shared__ float w1tS[32 * D];    // 16 KB

    int gid = blockIdx.x;
    const float* feat;
    _Float16* out;
    int off, base_row, nrows;
    if (gid < groupsU) {
        feat = ufeat; out = U; off = 0;
        base_row = gid * 64; nrows = n_users;
    } else {
        feat = ifeat; out = V; off = D;
        base_row = (gid - groupsU) * 64; nrows = n_movies;
    }

    int tid = threadIdx.x;

    for (int slot = tid; slot < (64 * D) / 4; slot += 256) {
        int row = slot >> 5;
        int k4  = slot & 31;
        int gr = base_row + row;
        if (gr >= nrows) gr = nrows - 1;
        *reinterpret_cast<float4*>(&featS[row * D + k4 * 4]) =
            *reinterpret_cast<const float4*>(&feat[(size_t)gr * D + k4 * 4]);
    }

    int sg = tid >> 5;
    int jj = tid & 31;

    float acc[8][4];
    #pragma unroll
    for (int r = 0; r < 8; ++r)
        #pragma unroll
        for (int c = 0; c < 4; ++c) acc[r][c] = 0.f;

    for (int kc = 0; kc < 4; ++kc) {
        __syncthreads();
        {
            int j  = tid >> 1;
            int kh = (tid & 1) * 16;
            const float* wp = &W1[(size_t)j * (2 * D) + off + kc * 32 + kh];
            float4 a0 = *reinterpret_cast<const float4*>(&wp[0]);
            float4 a1 = *reinterpret_cast<const float4*>(&wp[4]);
            float4 a2 = *reinterpret_cast<const float4*>(&wp[8]);
            float4 a3 = *reinterpret_cast<const float4*>(&wp[12]);
            w1tS[(kh + 0) * D + j] = a0.x;  w1tS[(kh + 1) * D + j] = a0.y;
            w1tS[(kh + 2) * D + j] = a0.z;  w1tS[(kh + 3) * D + j] = a0.w;
            w1tS[(kh + 4) * D + j] = a1.x;  w1tS[(kh + 5) * D + j] = a1.y;
            w1tS[(kh + 6) * D + j] = a1.z;  w1tS[(kh + 7) * D + j] = a1.w;
            w1tS[(kh + 8) * D + j] = a2.x;  w1tS[(kh + 9) * D + j] = a2.y;
            w1tS[(kh + 10) * D + j] = a2.z; w1tS[(kh + 11) * D + j] = a2.w;
            w1tS[(kh + 12) * D + j] = a3.x; w1tS[(kh + 13) * D + j] = a3.y;
            w1tS[(kh + 14) * D + j] = a3.z; w1tS[(kh + 15) * D + j] = a3.w;
        }
        __syncthreads();

        #pragma unroll 2
        for (int k4 = 0; k4 < 8; ++k4) {
            float4 wv0 = *reinterpret_cast<float4*>(&w1tS[(k4 * 4 + 0) * D + jj * 4]);
            float4 wv1 = *reinterpret_cast<float4*>(&w1tS[(k4 * 4 + 1) * D + jj * 4]);
            float4 wv2 = *reinterpret_cast<float4*>(&w1tS[(k4 * 4 + 2) * D + jj * 4]);
            float4 wv3 = *reinterpret_cast<float4*>(&w1tS[(k4 * 4 + 3) * D + jj * 4]);
            #pragma unroll
            for (int r = 0; r < 8; ++r) {
                float4 fv = *reinterpret_cast<float4*>(
                    &featS[(sg * 8 + r) * D + kc * 32 + k4 * 4]);
                acc[r][0] += fv.x * wv0.x; acc[r][1] += fv.x * wv0.y;
                acc[r][2] += fv.x * wv0.z; acc[r][3] += fv.x * wv0.w;
                acc[r][0] += fv.y * wv1.x; acc[r][1] += fv.y * wv1.y;
                acc[r][2] += fv.y * wv1.z; acc[r][3] += fv.y * wv1.w;
                acc[r][0] += fv.z * wv2.x; acc[r][1] += fv.z * wv2.y;
                acc[r][2] += fv.z * wv2.z; acc[r][3] += fv.z * wv2.w;
                acc[r][0] += fv.w * wv3.x; acc[r][1] += fv.w * wv3.y;
                acc[r][2] += fv.w * wv3.z; acc[r][3] += fv.w * wv3.w;
            }
        }
    }

    #pragma unroll
    for (int r = 0; r < 8; ++r) {
        int gr = base_row + sg * 8 + r;
        if (gr < nrows) {
            __half2 p0 = __floats2half2_rn(acc[r][0], acc[r][1]);
            __half2 p1 = __floats2half2_rn(acc[r][2], acc[r][3]);
            uint2 p;
            p.x = *reinterpret_cast<unsigned int*>(&p0);
            p.y = *reinterpret_cast<unsigned int*>(&p1);
            *reinterpret_cast<uint2*>(&out[(size_t)gr * D + jj * 4]) = p;
        }
    }
}

// ---------------------------------------------------------------------------
// Kernel 1b: W2h[16][128] fp16, rows 5..15 zero-padded (MFMA B operand).
// ---------------------------------------------------------------------------
__global__ __launch_bounds__(256) void convert_w2(
    const float* __restrict__ W2, _Float16* __restrict__ W2h)
{
    int idx = blockIdx.x * 256 + threadIdx.x;
    if (idx < 16 * D) {
        int r = idx >> 7;
        int k = idx & 127;
        float v = (r < C) ? W2[r * D + k] : 0.f;
        W2h[idx] = (_Float16)v;
    }
}

// ---------------------------------------------------------------------------
// Kernel 2: score = relu(U[src]+V[dst]) @ W2.T via MFMA 16x16x32 f16.
// Wave handles 16 edges. Lane l: A-row = l&15 (edge), k-group = l>>4.
// Gather 16 B fragments of U,V -> pk_add + pk_max (relu) -> MFMA x4 (K=128).
// C layout: col=l&15 (class), row=(l>>4)*4+j (edge). No LDS, no syncthreads.
// ---------------------------------------------------------------------------
__global__ __launch_bounds__(256) void edge_mlp(
    const _Float16* __restrict__ U, const _Float16* __restrict__ V,
    const _Float16* __restrict__ W2h,
    const int* __restrict__ src, const int* __restrict__ dst,
    float* __restrict__ out, int E)
{
    int tid = threadIdx.x;
    int w = tid >> 6;
    int l = tid & 63;
    int base = blockIdx.x * 64 + w * 16;
    int row16 = l & 15;
    int kg = l >> 4;

    // B fragments: W2h[col=row16][kb*32 + kg*8 .. +8]  (L2-resident, 4 KB)
    half8 bfrag[4];
    #pragma unroll
    for (int kb = 0; kb < 4; ++kb)
        bfrag[kb] = *reinterpret_cast<const half8*>(&W2h[row16 * D + kb * 32 + kg * 8]);

    int e = base + row16;
    int ec = (e < E) ? e : (E - 1);
    int s = src[ec];
    int d = dst[ec];
    const _Float16* up = &U[(size_t)s * D + kg * 8];
    const _Float16* vp = &V[(size_t)d * D + kg * 8];

    f32x4 acc = {0.f, 0.f, 0.f, 0.f};

    #pragma unroll
    for (int kb = 0; kb < 4; ++kb) {
        half8 au = *reinterpret_cast<const half8*>(&up[kb * 32]);
        half8 av = *reinterpret_cast<const half8*>(&vp[kb * 32]);
        half8 h = __builtin_elementwise_max(au + av, (half8)(_Float16)0.f);
        acc = __builtin_amdgcn_mfma_f32_16x16x32_f16(h, bfrag[kb], acc, 0, 0, 0);
    }

    int col = row16;
    if (col < C) {
        #pragma unroll
        for (int j = 0; j < 4; ++j) {
            int er = base + kg * 4 + j;
            if (er < E) out[(size_t)er * C + col] = acc[j];
        }
    }
}

extern "C" void kernel_launch(void* const* d_in, const int* in_sizes, int n_in,
                              void* d_out, int out_size, void* d_ws, size_t ws_size,
                              hipStream_t stream) {
    (void)n_in; (void)out_size; (void)ws_size;
    const float* ufeat = (const float*)d_in[0];
    const float* ifeat = (const float*)d_in[1];
    const float* W1    = (const float*)d_in[2];
    const float* W2    = (const float*)d_in[3];
    const int*   src   = (const int*)d_in[4];
    const int*   dst   = (const int*)d_in[5];

    int n_users  = in_sizes[0] / D;
    int n_movies = in_sizes[1] / D;
    int E        = in_sizes[4];

    float* out = (float*)d_out;
    _Float16* Ubuf = (_Float16*)d_ws;                    // n_users*128 fp16
    _Float16* Vbuf = Ubuf + (size_t)n_users * D;         // n_movies*128 fp16
    _Float16* W2h  = Vbuf + (size_t)n_movies * D;        // 16*128 fp16 (padded)

    int groupsU = (n_users + 63) / 64;
    int groupsV = (n_movies + 63) / 64;
    precompute_uv<<<groupsU + groupsV, 256, 0, stream>>>(
        ufeat, ifeat, W1, Ubuf, Vbuf, n_users, n_movies, groupsU);
    convert_w2<<<8, 256, 0, stream>>>(W2, W2h);

    int eblocks = (E + 63) / 64;
    edge_mlp<<<eblocks, 256, 0, stream>>>(Ubuf, Vbuf, W2h, src, dst, out, E);
}

// Round 4
// 135.192 us; speedup vs baseline: 3.2540x; 1.2064x over previous
//
#include <hip/hip_runtime.h>
#include <hip/hip_fp16.h>

#define D 128
#define C 5

typedef _Float16 half8 __attribute__((ext_vector_type(8)));
typedef float f32x4 __attribute__((ext_vector_type(4)));
typedef float f32x8 __attribute__((ext_vector_type(8)));

// ---------------------------------------------------------------------------
// Kernel 0: convert W1 (128x256 fp32) -> W1h fp16 (same layout) and
//           W2 (5x128 fp32) -> W2h fp16 [16][128] zero-padded.
// ---------------------------------------------------------------------------
__global__ __launch_bounds__(256) void convert_weights(
    const float* __restrict__ W1, const float* __restrict__ W2,
    _Float16* __restrict__ W1h, _Float16* __restrict__ W2h)
{
    int idx = blockIdx.x * 256 + threadIdx.x;
    if (idx < D * 2 * D) {
        W1h[idx] = (_Float16)W1[idx];
    } else {
        int j = idx - D * 2 * D;
        if (j < 16 * D) {
            int r = j >> 7;
            int k = j & 127;
            W2h[j] = (_Float16)((r < C) ? W2[r * D + k] : 0.f);
        }
    }
}

// ---------------------------------------------------------------------------
// Kernel 1: U = ufeat @ W1[:, :128].T ; V = ifeat @ W1[:, 128:].T  (fp16 out)
// via mfma_f32_16x16x32_f16. Block = 256 = 4 waves; wave owns 16 rows x 128
// cols, K=128. A-frag: lane reads 8 contiguous fp32 from its feat row,
// converts to fp16. B-frag: read straight from W1h row-major (B[k][j] =
// W1h[j][off+k] -> 16 B contiguous per lane). C layout: col=l&15,
// row=(l>>4)*4+j (verified pattern from edge_mlp). No LDS.
// ---------------------------------------------------------------------------
__global__ __launch_bounds__(256) void precompute_uv(
    const float* __restrict__ ufeat, const float* __restrict__ ifeat,
    const _Float16* __restrict__ W1h, _Float16* __restrict__ U,
    _Float16* __restrict__ V, int n_users, int n_movies, int groupsU)
{
    int gid = blockIdx.x;
    const float* feat;
    _Float16* out;
    int off, base_row, nrows;
    if (gid < groupsU) {
        feat = ufeat; out = U; off = 0;
        base_row = gid * 64; nrows = n_users;
    } else {
        feat = ifeat; out = V; off = D;
        base_row = (gid - groupsU) * 64; nrows = n_movies;
    }

    int tid = threadIdx.x;
    int w = tid >> 6;
    int l = tid & 63;
    int row16 = l & 15;
    int kg = l >> 4;

    int ra = base_row + w * 16 + row16;          // A-row this lane feeds
    int rc = (ra < nrows) ? ra : (nrows - 1);    // clamp loads; stores guarded
    const float* fp = feat + (size_t)rc * D + kg * 8;

    // A fragments: k = kb*32 + kg*8 .. +8
    half8 afrag[4];
    #pragma unroll
    for (int kb = 0; kb < 4; ++kb) {
        f32x8 f = *reinterpret_cast<const f32x8*>(&fp[kb * 32]);
        afrag[kb] = __builtin_convertvector(f, half8);
    }

    const _Float16* bp = W1h + off + kg * 8;
    int row0 = base_row + w * 16 + kg * 4;       // C-row base for this lane

    #pragma unroll
    for (int jt = 0; jt < 8; ++jt) {
        int col = jt * 16 + row16;               // B/C column
        const _Float16* bcol = bp + (size_t)col * (2 * D);
        f32x4 acc = {0.f, 0.f, 0.f, 0.f};
        #pragma unroll
        for (int kb = 0; kb < 4; ++kb) {
            half8 b = *reinterpret_cast<const half8*>(&bcol[kb * 32]);
            acc = __builtin_amdgcn_mfma_f32_16x16x32_f16(afrag[kb], b, acc, 0, 0, 0);
        }
        #pragma unroll
        for (int j = 0; j < 4; ++j) {
            int r = row0 + j;
            if (r < nrows) out[(size_t)r * D + col] = (_Float16)acc[j];
        }
    }
}

// ---------------------------------------------------------------------------
// Kernel 2: score = relu(U[src]+V[dst]) @ W2.T via MFMA 16x16x32 f16.
// Wave handles 32 edges (two 16-edge groups sharing one W2 B-frag) to double
// outstanding gathers per wave. Lane l: A-row = l&15, k-group = l>>4.
// ---------------------------------------------------------------------------
__global__ __launch_bounds__(256) void edge_mlp(
    const _Float16* __restrict__ U, const _Float16* __restrict__ V,
    const _Float16* __restrict__ W2h,
    const int* __restrict__ src, const int* __restrict__ dst,
    float* __restrict__ out, int E)
{
    int tid = threadIdx.x;
    int w = tid >> 6;
    int l = tid & 63;
    int base = blockIdx.x * 128 + w * 32;
    int row16 = l & 15;
    int kg = l >> 4;

    // B fragments (shared by both edge groups)
    half8 bfrag[4];
    #pragma unroll
    for (int kb = 0; kb < 4; ++kb)
        bfrag[kb] = *reinterpret_cast<const half8*>(&W2h[row16 * D + kb * 32 + kg * 8]);

    // Indices: lane (l&31) loads edge base+(l&31); shfl-broadcast.
    int i32 = base + (l & 31);
    int ic = (i32 < E) ? i32 : (E - 1);
    int sv = src[ic];
    int dv = dst[ic];
    int sA = __shfl(sv, row16);
    int dA = __shfl(dv, row16);
    int sB = __shfl(sv, 16 + row16);
    int dB = __shfl(dv, 16 + row16);

    const _Float16* upA = &U[(size_t)sA * D + kg * 8];
    const _Float16* vpA = &V[(size_t)dA * D + kg * 8];
    const _Float16* upB = &U[(size_t)sB * D + kg * 8];
    const _Float16* vpB = &V[(size_t)dB * D + kg * 8];

    f32x4 accA = {0.f, 0.f, 0.f, 0.f};
    f32x4 accB = {0.f, 0.f, 0.f, 0.f};

    #pragma unroll
    for (int kb = 0; kb < 4; ++kb) {
        half8 auA = *reinterpret_cast<const half8*>(&upA[kb * 32]);
        half8 avA = *reinterpret_cast<const half8*>(&vpA[kb * 32]);
        half8 auB = *reinterpret_cast<const half8*>(&upB[kb * 32]);
        half8 avB = *reinterpret_cast<const half8*>(&vpB[kb * 32]);
        half8 hA = __builtin_elementwise_max(auA + avA, (half8)(_Float16)0.f);
        half8 hB = __builtin_elementwise_max(auB + avB, (half8)(_Float16)0.f);
        accA = __builtin_amdgcn_mfma_f32_16x16x32_f16(hA, bfrag[kb], accA, 0, 0, 0);
        accB = __builtin_amdgcn_mfma_f32_16x16x32_f16(hB, bfrag[kb], accB, 0, 0, 0);
    }

    int col = row16;
    if (col < C) {
        #pragma unroll
        for (int j = 0; j < 4; ++j) {
            int erA = base + kg * 4 + j;
            if (erA < E) out[(size_t)erA * C + col] = accA[j];
            int erB = base + 16 + kg * 4 + j;
            if (erB < E) out[(size_t)erB * C + col] = accB[j];
        }
    }
}

extern "C" void kernel_launch(void* const* d_in, const int* in_sizes, int n_in,
                              void* d_out, int out_size, void* d_ws, size_t ws_size,
                              hipStream_t stream) {
    (void)n_in; (void)out_size; (void)ws_size;
    const float* ufeat = (const float*)d_in[0];
    const float* ifeat = (const float*)d_in[1];
    const float* W1    = (const float*)d_in[2];
    const float* W2    = (const float*)d_in[3];
    const int*   src   = (const int*)d_in[4];
    const int*   dst   = (const int*)d_in[5];

    int n_users  = in_sizes[0] / D;
    int n_movies = in_sizes[1] / D;
    int E        = in_sizes[4];

    float* out = (float*)d_out;
    _Float16* Ubuf = (_Float16*)d_ws;                    // n_users*128 fp16
    _Float16* Vbuf = Ubuf + (size_t)n_users * D;         // n_movies*128 fp16
    _Float16* W2h  = Vbuf + (size_t)n_movies * D;        // 16*128 fp16
    _Float16* W1h  = W2h + 16 * D;                       // 128*256 fp16

    convert_weights<<<(D * 2 * D + 16 * D + 255) / 256, 256, 0, stream>>>(
        W1, W2, W1h, W2h);

    int groupsU = (n_users + 63) / 64;
    int groupsV = (n_movies + 63) / 64;
    precompute_uv<<<groupsU + groupsV, 256, 0, stream>>>(
        ufeat, ifeat, W1h, Ubuf, Vbuf, n_users, n_movies, groupsU);

    int eblocks = (E + 127) / 128;
    edge_mlp<<<eblocks, 256, 0, stream>>>(Ubuf, Vbuf, W2h, src, dst, out, E);
}

// Round 5
// 112.670 us; speedup vs baseline: 3.9044x; 1.1999x over previous
//
#include <hip/hip_runtime.h>
#include <hip/hip_fp16.h>

#define D 128
#define C 5

typedef _Float16 half8 __attribute__((ext_vector_type(8)));
typedef float f32x4 __attribute__((ext_vector_type(4)));
typedef float f32x8 __attribute__((ext_vector_type(8)));

// ---------------------------------------------------------------------------
// Kernel 0: W1 (128x256 fp32) -> W1h fp16 (same layout);
//           W2 (5x128 fp32)   -> W2h fp16 [16][128] zero-padded.
// ---------------------------------------------------------------------------
__global__ __launch_bounds__(256) void convert_weights(
    const float* __restrict__ W1, const float* __restrict__ W2,
    _Float16* __restrict__ W1h, _Float16* __restrict__ W2h)
{
    int idx = blockIdx.x * 256 + threadIdx.x;
    if (idx < D * 2 * D) {
        W1h[idx] = (_Float16)W1[idx];
    } else {
        int j = idx - D * 2 * D;
        if (j < 16 * D) {
            int r = j >> 7;
            int k = j & 127;
            W2h[j] = (_Float16)((r < C) ? W2[r * D + k] : 0.f);
        }
    }
}

// ---------------------------------------------------------------------------
// Kernel 1: U = ufeat @ W1[:, :128].T ; V = ifeat @ W1[:, 128:].T  (fp16 out)
// Block = 256 threads = 4 waves; block covers 256 rows (wave: 64 rows x 128
// cols, K=128, via mfma_f32_16x16x32_f16).
// - W1-half staged in LDS once per block (32 KB), XOR-swizzled
//   (byte ^= (col&7)<<4) so B-frag reads (16 lanes at 256-B stride) are
//   ~2-way instead of 32-way bank conflicted.
// - A (64 rows) held in registers as fp16 fragments: 4 tiles x 4 kb x half8.
// - Per jt (16 cols): 4 B-frags from LDS, 16 MFMAs (4 independent chains).
// C layout: col = l&15, row = (l>>4)*4 + j  (verified in edge_mlp R3/R4).
// ---------------------------------------------------------------------------
__global__ __launch_bounds__(256) void precompute_uv(
    const float* __restrict__ ufeat, const float* __restrict__ ifeat,
    const _Float16* __restrict__ W1h, _Float16* __restrict__ U,
    _Float16* __restrict__ V, int n_users, int n_movies, int groupsU)
{
    __shared__ _Float16 ldsB[128 * 128];   // 32 KB, swizzled layout
    char* lb = (char*)ldsB;

    int gid = blockIdx.x;
    const float* feat;
    _Float16* out;
    int off, base_row, nrows;
    if (gid < groupsU) {
        feat = ufeat; out = U; off = 0;
        base_row = gid * 256; nrows = n_users;
    } else {
        feat = ifeat; out = V; off = D;
        base_row = (gid - groupsU) * 256; nrows = n_movies;
    }

    int tid = threadIdx.x;
    int w = tid >> 6;
    int l = tid & 63;
    int row16 = l & 15;
    int kg = l >> 4;

    // --- Stage W1 half into LDS (swizzled). 32 KB / 256 thr = 8 x 16 B each.
    {
        const char* wbase = (const char*)W1h + off * 2;
        #pragma unroll
        for (int i = 0; i < 8; ++i) {
            int lin = (tid + i * 256) * 16;       // linear byte in 32 KB half
            int col = lin >> 8;                   // 256 B per col-row
            int within = lin & 255;
            const char* srcp = wbase + (size_t)col * 512 + within;
            int dstb = lin ^ ((col & 7) << 4);
            *reinterpret_cast<uint4*>(lb + dstb) =
                *reinterpret_cast<const uint4*>(srcp);
        }
    }

    // --- A fragments: 64 rows for this wave, fp32 -> fp16 in registers.
    int rbase = base_row + w * 64;
    half8 afrag[4][4];   // [tile][kb]
    #pragma unroll
    for (int t = 0; t < 4; ++t) {
        int ra = rbase + t * 16 + row16;
        int rc = (ra < nrows) ? ra : (nrows - 1);
        const float* fp = feat + (size_t)rc * D + kg * 8;
        #pragma unroll
        for (int kb = 0; kb < 4; ++kb) {
            f32x8 f = *reinterpret_cast<const f32x8*>(&fp[kb * 32]);
            afrag[t][kb] = __builtin_convertvector(f, half8);
        }
    }
    __syncthreads();

    // --- Main loop over column groups.
    #pragma unroll 2
    for (int jt = 0; jt < 8; ++jt) {
        int col = jt * 16 + row16;
        int sw = (col & 7) << 4;
        int bb = col * 256 + kg * 16;
        half8 b0 = *reinterpret_cast<const half8*>(lb + ((bb +   0) ^ sw));
        half8 b1 = *reinterpret_cast<const half8*>(lb + ((bb +  64) ^ sw));
        half8 b2 = *reinterpret_cast<const half8*>(lb + ((bb + 128) ^ sw));
        half8 b3 = *reinterpret_cast<const half8*>(lb + ((bb + 192) ^ sw));

        f32x4 acc0 = {0.f, 0.f, 0.f, 0.f};
        f32x4 acc1 = {0.f, 0.f, 0.f, 0.f};
        f32x4 acc2 = {0.f, 0.f, 0.f, 0.f};
        f32x4 acc3 = {0.f, 0.f, 0.f, 0.f};
        acc0 = __builtin_amdgcn_mfma_f32_16x16x32_f16(afrag[0][0], b0, acc0, 0, 0, 0);
        acc1 = __builtin_amdgcn_mfma_f32_16x16x32_f16(afrag[1][0], b0, acc1, 0, 0, 0);
        acc2 = __builtin_amdgcn_mfma_f32_16x16x32_f16(afrag[2][0], b0, acc2, 0, 0, 0);
        acc3 = __builtin_amdgcn_mfma_f32_16x16x32_f16(afrag[3][0], b0, acc3, 0, 0, 0);
        acc0 = __builtin_amdgcn_mfma_f32_16x16x32_f16(afrag[0][1], b1, acc0, 0, 0, 0);
        acc1 = __builtin_amdgcn_mfma_f32_16x16x32_f16(afrag[1][1], b1, acc1, 0, 0, 0);
        acc2 = __builtin_amdgcn_mfma_f32_16x16x32_f16(afrag[2][1], b1, acc2, 0, 0, 0);
        acc3 = __builtin_amdgcn_mfma_f32_16x16x32_f16(afrag[3][1], b1, acc3, 0, 0, 0);
        acc0 = __builtin_amdgcn_mfma_f32_16x16x32_f16(afrag[0][2], b2, acc0, 0, 0, 0);
        acc1 = __builtin_amdgcn_mfma_f32_16x16x32_f16(afrag[1][2], b2, acc1, 0, 0, 0);
        acc2 = __builtin_amdgcn_mfma_f32_16x16x32_f16(afrag[2][2], b2, acc2, 0, 0, 0);
        acc3 = __builtin_amdgcn_mfma_f32_16x16x32_f16(afrag[3][2], b2, acc3, 0, 0, 0);
        acc0 = __builtin_amdgcn_mfma_f32_16x16x32_f16(afrag[0][3], b3, acc0, 0, 0, 0);
        acc1 = __builtin_amdgcn_mfma_f32_16x16x32_f16(afrag[1][3], b3, acc1, 0, 0, 0);
        acc2 = __builtin_amdgcn_mfma_f32_16x16x32_f16(afrag[2][3], b3, acc2, 0, 0, 0);
        acc3 = __builtin_amdgcn_mfma_f32_16x16x32_f16(afrag[3][3], b3, acc3, 0, 0, 0);

        int r0 = rbase + kg * 4;
        #pragma unroll
        for (int j = 0; j < 4; ++j) {
            int r = r0 + j;
            if (r +  0 < nrows) out[(size_t)(r +  0) * D + col] = (_Float16)acc0[j];
            if (r + 16 < nrows) out[(size_t)(r + 16) * D + col] = (_Float16)acc1[j];
            if (r + 32 < nrows) out[(size_t)(r + 32) * D + col] = (_Float16)acc2[j];
            if (r + 48 < nrows) out[(size_t)(r + 48) * D + col] = (_Float16)acc3[j];
        }
    }
}

// ---------------------------------------------------------------------------
// Kernel 2 (unchanged from R4 — at gather-fabric ceiling):
// score = relu(U[src]+V[dst]) @ W2.T via MFMA 16x16x32 f16, 32 edges/wave.
// ---------------------------------------------------------------------------
__global__ __launch_bounds__(256) void edge_mlp(
    const _Float16* __restrict__ U, const _Float16* __restrict__ V,
    const _Float16* __restrict__ W2h,
    const int* __restrict__ src, const int* __restrict__ dst,
    float* __restrict__ out, int E)
{
    int tid = threadIdx.x;
    int w = tid >> 6;
    int l = tid & 63;
    int base = blockIdx.x * 128 + w * 32;
    int row16 = l & 15;
    int kg = l >> 4;

    half8 bfrag[4];
    #pragma unroll
    for (int kb = 0; kb < 4; ++kb)
        bfrag[kb] = *reinterpret_cast<const half8*>(&W2h[row16 * D + kb * 32 + kg * 8]);

    int i32 = base + (l & 31);
    int ic = (i32 < E) ? i32 : (E - 1);
    int sv = src[ic];
    int dv = dst[ic];
    int sA = __shfl(sv, row16);
    int dA = __shfl(dv, row16);
    int sB = __shfl(sv, 16 + row16);
    int dB = __shfl(dv, 16 + row16);

    const _Float16* upA = &U[(size_t)sA * D + kg * 8];
    const _Float16* vpA = &V[(size_t)dA * D + kg * 8];
    const _Float16* upB = &U[(size_t)sB * D + kg * 8];
    const _Float16* vpB = &V[(size_t)dB * D + kg * 8];

    f32x4 accA = {0.f, 0.f, 0.f, 0.f};
    f32x4 accB = {0.f, 0.f, 0.f, 0.f};

    #pragma unroll
    for (int kb = 0; kb < 4; ++kb) {
        half8 auA = *reinterpret_cast<const half8*>(&upA[kb * 32]);
        half8 avA = *reinterpret_cast<const half8*>(&vpA[kb * 32]);
        half8 auB = *reinterpret_cast<const half8*>(&upB[kb * 32]);
        half8 avB = *reinterpret_cast<const half8*>(&vpB[kb * 32]);
        half8 hA = __builtin_elementwise_max(auA + avA, (half8)(_Float16)0.f);
        half8 hB = __builtin_elementwise_max(auB + avB, (half8)(_Float16)0.f);
        accA = __builtin_amdgcn_mfma_f32_16x16x32_f16(hA, bfrag[kb], accA, 0, 0, 0);
        accB = __builtin_amdgcn_mfma_f32_16x16x32_f16(hB, bfrag[kb], accB, 0, 0, 0);
    }

    int col = row16;
    if (col < C) {
        #pragma unroll
        for (int j = 0; j < 4; ++j) {
            int erA = base + kg * 4 + j;
            if (erA < E) out[(size_t)erA * C + col] = accA[j];
            int erB = base + 16 + kg * 4 + j;
            if (erB < E) out[(size_t)erB * C + col] = accB[j];
        }
    }
}

extern "C" void kernel_launch(void* const* d_in, const int* in_sizes, int n_in,
                              void* d_out, int out_size, void* d_ws, size_t ws_size,
                              hipStream_t stream) {
    (void)n_in; (void)out_size; (void)ws_size;
    const float* ufeat = (const float*)d_in[0];
    const float* ifeat = (const float*)d_in[1];
    const float* W1    = (const float*)d_in[2];
    const float* W2    = (const float*)d_in[3];
    const int*   src   = (const int*)d_in[4];
    const int*   dst   = (const int*)d_in[5];

    int n_users  = in_sizes[0] / D;
    int n_movies = in_sizes[1] / D;
    int E        = in_sizes[4];

    float* out = (float*)d_out;
    _Float16* Ubuf = (_Float16*)d_ws;                    // n_users*128 fp16
    _Float16* Vbuf = Ubuf + (size_t)n_users * D;         // n_movies*128 fp16
    _Float16* W2h  = Vbuf + (size_t)n_movies * D;        // 16*128 fp16
    _Float16* W1h  = W2h + 16 * D;                       // 128*256 fp16

    convert_weights<<<(D * 2 * D + 16 * D + 255) / 256, 256, 0, stream>>>(
        W1, W2, W1h, W2h);

    int groupsU = (n_users + 255) / 256;
    int groupsV = (n_movies + 255) / 256;
    precompute_uv<<<groupsU + groupsV, 256, 0, stream>>>(
        ufeat, ifeat, W1h, Ubuf, Vbuf, n_users, n_movies, groupsU);

    int eblocks = (E + 127) / 128;
    edge_mlp<<<eblocks, 256, 0, stream>>>(Ubuf, Vbuf, W2h, src, dst, out, E);
}

// Round 6
// 111.286 us; speedup vs baseline: 3.9530x; 1.0124x over previous
//
#include <hip/hip_runtime.h>
#include <hip/hip_fp16.h>

#define D 128
#define C 5

typedef _Float16 half8 __attribute__((ext_vector_type(8)));
typedef float f32x4 __attribute__((ext_vector_type(4)));
typedef float f32x8 __attribute__((ext_vector_type(8)));

// ---------------------------------------------------------------------------
// Kernel 0: W1 (128x256 fp32) -> W1h fp16 (same layout);
//           W2 (5x128 fp32)   -> W2h fp16 [16][128] zero-padded.
// ---------------------------------------------------------------------------
__global__ __launch_bounds__(256) void convert_weights(
    const float* __restrict__ W1, const float* __restrict__ W2,
    _Float16* __restrict__ W1h, _Float16* __restrict__ W2h)
{
    int idx = blockIdx.x * 256 + threadIdx.x;
    if (idx < D * 2 * D) {
        W1h[idx] = (_Float16)W1[idx];
    } else {
        int j = idx - D * 2 * D;
        if (j < 16 * D) {
            int r = j >> 7;
            int k = j & 127;
            W2h[j] = (_Float16)((r < C) ? W2[r * D + k] : 0.f);
        }
    }
}

// ---------------------------------------------------------------------------
// Kernel 1 (unchanged from R5): U/V precompute via MFMA, LDS-swizzled B,
// A in registers, 4 independent accumulator chains.
// ---------------------------------------------------------------------------
__global__ __launch_bounds__(256) void precompute_uv(
    const float* __restrict__ ufeat, const float* __restrict__ ifeat,
    const _Float16* __restrict__ W1h, _Float16* __restrict__ U,
    _Float16* __restrict__ V, int n_users, int n_movies, int groupsU)
{
    __shared__ _Float16 ldsB[128 * 128];   // 32 KB, swizzled layout
    char* lb = (char*)ldsB;

    int gid = blockIdx.x;
    const float* feat;
    _Float16* out;
    int off, base_row, nrows;
    if (gid < groupsU) {
        feat = ufeat; out = U; off = 0;
        base_row = gid * 256; nrows = n_users;
    } else {
        feat = ifeat; out = V; off = D;
        base_row = (gid - groupsU) * 256; nrows = n_movies;
    }

    int tid = threadIdx.x;
    int w = tid >> 6;
    int l = tid & 63;
    int row16 = l & 15;
    int kg = l >> 4;

    {
        const char* wbase = (const char*)W1h + off * 2;
        #pragma unroll
        for (int i = 0; i < 8; ++i) {
            int lin = (tid + i * 256) * 16;
            int col = lin >> 8;
            int within = lin & 255;
            const char* srcp = wbase + (size_t)col * 512 + within;
            int dstb = lin ^ ((col & 7) << 4);
            *reinterpret_cast<uint4*>(lb + dstb) =
                *reinterpret_cast<const uint4*>(srcp);
        }
    }

    int rbase = base_row + w * 64;
    half8 afrag[4][4];
    #pragma unroll
    for (int t = 0; t < 4; ++t) {
        int ra = rbase + t * 16 + row16;
        int rc = (ra < nrows) ? ra : (nrows - 1);
        const float* fp = feat + (size_t)rc * D + kg * 8;
        #pragma unroll
        for (int kb = 0; kb < 4; ++kb) {
            f32x8 f = *reinterpret_cast<const f32x8*>(&fp[kb * 32]);
            afrag[t][kb] = __builtin_convertvector(f, half8);
        }
    }
    __syncthreads();

    #pragma unroll 2
    for (int jt = 0; jt < 8; ++jt) {
        int col = jt * 16 + row16;
        int sw = (col & 7) << 4;
        int bb = col * 256 + kg * 16;
        half8 b0 = *reinterpret_cast<const half8*>(lb + ((bb +   0) ^ sw));
        half8 b1 = *reinterpret_cast<const half8*>(lb + ((bb +  64) ^ sw));
        half8 b2 = *reinterpret_cast<const half8*>(lb + ((bb + 128) ^ sw));
        half8 b3 = *reinterpret_cast<const half8*>(lb + ((bb + 192) ^ sw));

        f32x4 acc0 = {0.f, 0.f, 0.f, 0.f};
        f32x4 acc1 = {0.f, 0.f, 0.f, 0.f};
        f32x4 acc2 = {0.f, 0.f, 0.f, 0.f};
        f32x4 acc3 = {0.f, 0.f, 0.f, 0.f};
        acc0 = __builtin_amdgcn_mfma_f32_16x16x32_f16(afrag[0][0], b0, acc0, 0, 0, 0);
        acc1 = __builtin_amdgcn_mfma_f32_16x16x32_f16(afrag[1][0], b0, acc1, 0, 0, 0);
        acc2 = __builtin_amdgcn_mfma_f32_16x16x32_f16(afrag[2][0], b0, acc2, 0, 0, 0);
        acc3 = __builtin_amdgcn_mfma_f32_16x16x32_f16(afrag[3][0], b0, acc3, 0, 0, 0);
        acc0 = __builtin_amdgcn_mfma_f32_16x16x32_f16(afrag[0][1], b1, acc0, 0, 0, 0);
        acc1 = __builtin_amdgcn_mfma_f32_16x16x32_f16(afrag[1][1], b1, acc1, 0, 0, 0);
        acc2 = __builtin_amdgcn_mfma_f32_16x16x32_f16(afrag[2][1], b1, acc2, 0, 0, 0);
        acc3 = __builtin_amdgcn_mfma_f32_16x16x32_f16(afrag[3][1], b1, acc3, 0, 0, 0);
        acc0 = __builtin_amdgcn_mfma_f32_16x16x32_f16(afrag[0][2], b2, acc0, 0, 0, 0);
        acc1 = __builtin_amdgcn_mfma_f32_16x16x32_f16(afrag[1][2], b2, acc1, 0, 0, 0);
        acc2 = __builtin_amdgcn_mfma_f32_16x16x32_f16(afrag[2][2], b2, acc2, 0, 0, 0);
        acc3 = __builtin_amdgcn_mfma_f32_16x16x32_f16(afrag[3][2], b2, acc3, 0, 0, 0);
        acc0 = __builtin_amdgcn_mfma_f32_16x16x32_f16(afrag[0][3], b3, acc0, 0, 0, 0);
        acc1 = __builtin_amdgcn_mfma_f32_16x16x32_f16(afrag[1][3], b3, acc1, 0, 0, 0);
        acc2 = __builtin_amdgcn_mfma_f32_16x16x32_f16(afrag[2][3], b3, acc2, 0, 0, 0);
        acc3 = __builtin_amdgcn_mfma_f32_16x16x32_f16(afrag[3][3], b3, acc3, 0, 0, 0);

        int r0 = rbase + kg * 4;
        #pragma unroll
        for (int j = 0; j < 4; ++j) {
            int r = r0 + j;
            if (r +  0 < nrows) out[(size_t)(r +  0) * D + col] = (_Float16)acc0[j];
            if (r + 16 < nrows) out[(size_t)(r + 16) * D + col] = (_Float16)acc1[j];
            if (r + 32 < nrows) out[(size_t)(r + 32) * D + col] = (_Float16)acc2[j];
            if (r + 48 < nrows) out[(size_t)(r + 48) * D + col] = (_Float16)acc3[j];
        }
    }
}

// ---------------------------------------------------------------------------
// Kernel 2: score = relu(U[src]+V[dst]) @ W2.T via MFMA 16x16x32 f16.
// Wave handles 64 edges (4 groups of 16 sharing one W2 B-frag) — doubles
// outstanding gathers per wave vs R5 to test concurrency- vs fabric-bound.
// kb-outer / group-inner: 8 loads issue per 4-MFMA burst; compiler hoists
// next-kb loads under current MFMAs.
// ---------------------------------------------------------------------------
__global__ __launch_bounds__(256) void edge_mlp(
    const _Float16* __restrict__ U, const _Float16* __restrict__ V,
    const _Float16* __restrict__ W2h,
    const int* __restrict__ src, const int* __restrict__ dst,
    float* __restrict__ out, int E)
{
    int tid = threadIdx.x;
    int w = tid >> 6;
    int l = tid & 63;
    int base = blockIdx.x * 256 + w * 64;
    int row16 = l & 15;
    int kg = l >> 4;

    // B fragments (shared by all 4 edge groups)
    half8 bfrag[4];
    #pragma unroll
    for (int kb = 0; kb < 4; ++kb)
        bfrag[kb] = *reinterpret_cast<const half8*>(&W2h[row16 * D + kb * 32 + kg * 8]);

    // Lane l loads edge base+l; shfl-broadcast per group.
    int i64 = base + l;
    int ic = (i64 < E) ? i64 : (E - 1);
    int sv = src[ic];
    int dv = dst[ic];

    const _Float16* up[4];
    const _Float16* vp[4];
    #pragma unroll
    for (int g = 0; g < 4; ++g) {
        int sg_ = __shfl(sv, g * 16 + row16);
        int dg_ = __shfl(dv, g * 16 + row16);
        up[g] = &U[(size_t)sg_ * D + kg * 8];
        vp[g] = &V[(size_t)dg_ * D + kg * 8];
    }

    f32x4 acc[4];
    #pragma unroll
    for (int g = 0; g < 4; ++g) acc[g] = (f32x4){0.f, 0.f, 0.f, 0.f};

    #pragma unroll
    for (int kb = 0; kb < 4; ++kb) {
        half8 au0 = *reinterpret_cast<const half8*>(&up[0][kb * 32]);
        half8 av0 = *reinterpret_cast<const half8*>(&vp[0][kb * 32]);
        half8 au1 = *reinterpret_cast<const half8*>(&up[1][kb * 32]);
        half8 av1 = *reinterpret_cast<const half8*>(&vp[1][kb * 32]);
        half8 au2 = *reinterpret_cast<const half8*>(&up[2][kb * 32]);
        half8 av2 = *reinterpret_cast<const half8*>(&vp[2][kb * 32]);
        half8 au3 = *reinterpret_cast<const half8*>(&up[3][kb * 32]);
        half8 av3 = *reinterpret_cast<const half8*>(&vp[3][kb * 32]);
        half8 h0 = __builtin_elementwise_max(au0 + av0, (half8)(_Float16)0.f);
        half8 h1 = __builtin_elementwise_max(au1 + av1, (half8)(_Float16)0.f);
        half8 h2 = __builtin_elementwise_max(au2 + av2, (half8)(_Float16)0.f);
        half8 h3 = __builtin_elementwise_max(au3 + av3, (half8)(_Float16)0.f);
        acc[0] = __builtin_amdgcn_mfma_f32_16x16x32_f16(h0, bfrag[kb], acc[0], 0, 0, 0);
        acc[1] = __builtin_amdgcn_mfma_f32_16x16x32_f16(h1, bfrag[kb], acc[1], 0, 0, 0);
        acc[2] = __builtin_amdgcn_mfma_f32_16x16x32_f16(h2, bfrag[kb], acc[2], 0, 0, 0);
        acc[3] = __builtin_amdgcn_mfma_f32_16x16x32_f16(h3, bfrag[kb], acc[3], 0, 0, 0);
    }

    int col = row16;
    if (col < C) {
        #pragma unroll
        for (int g = 0; g < 4; ++g) {
            #pragma unroll
            for (int j = 0; j < 4; ++j) {
                int er = base + g * 16 + kg * 4 + j;
                if (er < E) out[(size_t)er * C + col] = acc[g][j];
            }
        }
    }
}

extern "C" void kernel_launch(void* const* d_in, const int* in_sizes, int n_in,
                              void* d_out, int out_size, void* d_ws, size_t ws_size,
                              hipStream_t stream) {
    (void)n_in; (void)out_size; (void)ws_size;
    const float* ufeat = (const float*)d_in[0];
    const float* ifeat = (const float*)d_in[1];
    const float* W1    = (const float*)d_in[2];
    const float* W2    = (const float*)d_in[3];
    const int*   src   = (const int*)d_in[4];
    const int*   dst   = (const int*)d_in[5];

    int n_users  = in_sizes[0] / D;
    int n_movies = in_sizes[1] / D;
    int E        = in_sizes[4];

    float* out = (float*)d_out;
    _Float16* Ubuf = (_Float16*)d_ws;                    // n_users*128 fp16
    _Float16* Vbuf = Ubuf + (size_t)n_users * D;         // n_movies*128 fp16
    _Float16* W2h  = Vbuf + (size_t)n_movies * D;        // 16*128 fp16
    _Float16* W1h  = W2h + 16 * D;                       // 128*256 fp16

    convert_weights<<<(D * 2 * D + 16 * D + 255) / 256, 256, 0, stream>>>(
        W1, W2, W1h, W2h);

    int groupsU = (n_users + 255) / 256;
    int groupsV = (n_movies + 255) / 256;
    precompute_uv<<<groupsU + groupsV, 256, 0, stream>>>(
        ufeat, ifeat, W1h, Ubuf, Vbuf, n_users, n_movies, groupsU);

    int eblocks = (E + 255) / 256;
    edge_mlp<<<eblocks, 256, 0, stream>>>(Ubuf, Vbuf, W2h, src, dst, out, E);
}

// Round 7
// 104.637 us; speedup vs baseline: 4.2041x; 1.0635x over previous
//
#include <hip/hip_runtime.h>
#include <hip/hip_fp16.h>

#define D 128
#define C 5

typedef _Float16 half8 __attribute__((ext_vector_type(8)));
typedef float f32x4 __attribute__((ext_vector_type(4)));
typedef float f32x8 __attribute__((ext_vector_type(8)));

// ---------------------------------------------------------------------------
// Kernel 0: W1 (128x256 fp32) -> W1h fp16 (same layout);
//           W2 (5x128 fp32)   -> W2h fp16 [16][128] zero-padded.
// ---------------------------------------------------------------------------
__global__ __launch_bounds__(256) void convert_weights(
    const float* __restrict__ W1, const float* __restrict__ W2,
    _Float16* __restrict__ W1h, _Float16* __restrict__ W2h)
{
    int idx = blockIdx.x * 256 + threadIdx.x;
    if (idx < D * 2 * D) {
        W1h[idx] = (_Float16)W1[idx];
    } else {
        int j = idx - D * 2 * D;
        if (j < 16 * D) {
            int r = j >> 7;
            int k = j & 127;
            W2h[j] = (_Float16)((r < C) ? W2[r * D + k] : 0.f);
        }
    }
}

// ---------------------------------------------------------------------------
// Kernel 1: U/V precompute via MFMA. R7: 128 rows/block (32 rows/wave,
// 2 A-tiles x 4 kb in regs, 2 MFMA chains) -> 1173 blocks (~4.6/CU) lifts
// the grid-limited occupancy of R5/R6 (587 blocks, 2.3/CU). A-fragment
// global loads issued BEFORE LDS staging so HBM latency overlaps stage+sync.
// LDS: W1 half, 32 KB, XOR-swizzled (byte ^= (col&7)<<4).
// C layout: col = l&15, row = (l>>4)*4 + j.
// ---------------------------------------------------------------------------
__global__ __launch_bounds__(256) void precompute_uv(
    const float* __restrict__ ufeat, const float* __restrict__ ifeat,
    const _Float16* __restrict__ W1h, _Float16* __restrict__ U,
    _Float16* __restrict__ V, int n_users, int n_movies, int groupsU)
{
    __shared__ _Float16 ldsB[128 * 128];   // 32 KB, swizzled layout
    char* lb = (char*)ldsB;

    int gid = blockIdx.x;
    const float* feat;
    _Float16* out;
    int off, base_row, nrows;
    if (gid < groupsU) {
        feat = ufeat; out = U; off = 0;
        base_row = gid * 128; nrows = n_users;
    } else {
        feat = ifeat; out = V; off = D;
        base_row = (gid - groupsU) * 128; nrows = n_movies;
    }

    int tid = threadIdx.x;
    int w = tid >> 6;
    int l = tid & 63;
    int row16 = l & 15;
    int kg = l >> 4;

    // --- A fragments first (HBM loads in flight during LDS staging).
    int rbase = base_row + w * 32;
    half8 afrag[2][4];   // [tile][kb]
    #pragma unroll
    for (int t = 0; t < 2; ++t) {
        int ra = rbase + t * 16 + row16;
        int rc = (ra < nrows) ? ra : (nrows - 1);
        const float* fp = feat + (size_t)rc * D + kg * 8;
        #pragma unroll
        for (int kb = 0; kb < 4; ++kb) {
            f32x8 f = *reinterpret_cast<const f32x8*>(&fp[kb * 32]);
            afrag[t][kb] = __builtin_convertvector(f, half8);
        }
    }

    // --- Stage W1 half into LDS (swizzled). 32 KB / 256 thr = 8 x 16 B.
    {
        const char* wbase = (const char*)W1h + off * 2;
        #pragma unroll
        for (int i = 0; i < 8; ++i) {
            int lin = (tid + i * 256) * 16;
            int col = lin >> 8;
            int within = lin & 255;
            const char* srcp = wbase + (size_t)col * 512 + within;
            int dstb = lin ^ ((col & 7) << 4);
            *reinterpret_cast<uint4*>(lb + dstb) =
                *reinterpret_cast<const uint4*>(srcp);
        }
    }
    __syncthreads();

    // --- Main loop over column groups.
    #pragma unroll 2
    for (int jt = 0; jt < 8; ++jt) {
        int col = jt * 16 + row16;
        int sw = (col & 7) << 4;
        int bb = col * 256 + kg * 16;
        half8 b0 = *reinterpret_cast<const half8*>(lb + ((bb +   0) ^ sw));
        half8 b1 = *reinterpret_cast<const half8*>(lb + ((bb +  64) ^ sw));
        half8 b2 = *reinterpret_cast<const half8*>(lb + ((bb + 128) ^ sw));
        half8 b3 = *reinterpret_cast<const half8*>(lb + ((bb + 192) ^ sw));

        f32x4 acc0 = {0.f, 0.f, 0.f, 0.f};
        f32x4 acc1 = {0.f, 0.f, 0.f, 0.f};
        acc0 = __builtin_amdgcn_mfma_f32_16x16x32_f16(afrag[0][0], b0, acc0, 0, 0, 0);
        acc1 = __builtin_amdgcn_mfma_f32_16x16x32_f16(afrag[1][0], b0, acc1, 0, 0, 0);
        acc0 = __builtin_amdgcn_mfma_f32_16x16x32_f16(afrag[0][1], b1, acc0, 0, 0, 0);
        acc1 = __builtin_amdgcn_mfma_f32_16x16x32_f16(afrag[1][1], b1, acc1, 0, 0, 0);
        acc0 = __builtin_amdgcn_mfma_f32_16x16x32_f16(afrag[0][2], b2, acc0, 0, 0, 0);
        acc1 = __builtin_amdgcn_mfma_f32_16x16x32_f16(afrag[1][2], b2, acc1, 0, 0, 0);
        acc0 = __builtin_amdgcn_mfma_f32_16x16x32_f16(afrag[0][3], b3, acc0, 0, 0, 0);
        acc1 = __builtin_amdgcn_mfma_f32_16x16x32_f16(afrag[1][3], b3, acc1, 0, 0, 0);

        int r0 = rbase + kg * 4;
        #pragma unroll
        for (int j = 0; j < 4; ++j) {
            int r = r0 + j;
            if (r +  0 < nrows) out[(size_t)(r +  0) * D + col] = (_Float16)acc0[j];
            if (r + 16 < nrows) out[(size_t)(r + 16) * D + col] = (_Float16)acc1[j];
        }
    }
}

// ---------------------------------------------------------------------------
// Kernel 2 (unchanged from R6 — at structural gather floor):
// score = relu(U[src]+V[dst]) @ W2.T via MFMA 16x16x32 f16, 64 edges/wave.
// ---------------------------------------------------------------------------
__global__ __launch_bounds__(256) void edge_mlp(
    const _Float16* __restrict__ U, const _Float16* __restrict__ V,
    const _Float16* __restrict__ W2h,
    const int* __restrict__ src, const int* __restrict__ dst,
    float* __restrict__ out, int E)
{
    int tid = threadIdx.x;
    int w = tid >> 6;
    int l = tid & 63;
    int base = blockIdx.x * 256 + w * 64;
    int row16 = l & 15;
    int kg = l >> 4;

    half8 bfrag[4];
    #pragma unroll
    for (int kb = 0; kb < 4; ++kb)
        bfrag[kb] = *reinterpret_cast<const half8*>(&W2h[row16 * D + kb * 32 + kg * 8]);

    int i64 = base + l;
    int ic = (i64 < E) ? i64 : (E - 1);
    int sv = src[ic];
    int dv = dst[ic];

    const _Float16* up[4];
    const _Float16* vp[4];
    #pragma unroll
    for (int g = 0; g < 4; ++g) {
        int sg_ = __shfl(sv, g * 16 + row16);
        int dg_ = __shfl(dv, g * 16 + row16);
        up[g] = &U[(size_t)sg_ * D + kg * 8];
        vp[g] = &V[(size_t)dg_ * D + kg * 8];
    }

    f32x4 acc[4];
    #pragma unroll
    for (int g = 0; g < 4; ++g) acc[g] = (f32x4){0.f, 0.f, 0.f, 0.f};

    #pragma unroll
    for (int kb = 0; kb < 4; ++kb) {
        half8 au0 = *reinterpret_cast<const half8*>(&up[0][kb * 32]);
        half8 av0 = *reinterpret_cast<const half8*>(&vp[0][kb * 32]);
        half8 au1 = *reinterpret_cast<const half8*>(&up[1][kb * 32]);
        half8 av1 = *reinterpret_cast<const half8*>(&vp[1][kb * 32]);
        half8 au2 = *reinterpret_cast<const half8*>(&up[2][kb * 32]);
        half8 av2 = *reinterpret_cast<const half8*>(&vp[2][kb * 32]);
        half8 au3 = *reinterpret_cast<const half8*>(&up[3][kb * 32]);
        half8 av3 = *reinterpret_cast<const half8*>(&vp[3][kb * 32]);
        half8 h0 = __builtin_elementwise_max(au0 + av0, (half8)(_Float16)0.f);
        half8 h1 = __builtin_elementwise_max(au1 + av1, (half8)(_Float16)0.f);
        half8 h2 = __builtin_elementwise_max(au2 + av2, (half8)(_Float16)0.f);
        half8 h3 = __builtin_elementwise_max(au3 + av3, (half8)(_Float16)0.f);
        acc[0] = __builtin_amdgcn_mfma_f32_16x16x32_f16(h0, bfrag[kb], acc[0], 0, 0, 0);
        acc[1] = __builtin_amdgcn_mfma_f32_16x16x32_f16(h1, bfrag[kb], acc[1], 0, 0, 0);
        acc[2] = __builtin_amdgcn_mfma_f32_16x16x32_f16(h2, bfrag[kb], acc[2], 0, 0, 0);
        acc[3] = __builtin_amdgcn_mfma_f32_16x16x32_f16(h3, bfrag[kb], acc[3], 0, 0, 0);
    }

    int col = row16;
    if (col < C) {
        #pragma unroll
        for (int g = 0; g < 4; ++g) {
            #pragma unroll
            for (int j = 0; j < 4; ++j) {
                int er = base + g * 16 + kg * 4 + j;
                if (er < E) out[(size_t)er * C + col] = acc[g][j];
            }
        }
    }
}

extern "C" void kernel_launch(void* const* d_in, const int* in_sizes, int n_in,
                              void* d_out, int out_size, void* d_ws, size_t ws_size,
                              hipStream_t stream) {
    (void)n_in; (void)out_size; (void)ws_size;
    const float* ufeat = (const float*)d_in[0];
    const float* ifeat = (const float*)d_in[1];
    const float* W1    = (const float*)d_in[2];
    const float* W2    = (const float*)d_in[3];
    const int*   src   = (const int*)d_in[4];
    const int*   dst   = (const int*)d_in[5];

    int n_users  = in_sizes[0] / D;
    int n_movies = in_sizes[1] / D;
    int E        = in_sizes[4];

    float* out = (float*)d_out;
    _Float16* Ubuf = (_Float16*)d_ws;                    // n_users*128 fp16
    _Float16* Vbuf = Ubuf + (size_t)n_users * D;         // n_movies*128 fp16
    _Float16* W2h  = Vbuf + (size_t)n_movies * D;        // 16*128 fp16
    _Float16* W1h  = W2h + 16 * D;                       // 128*256 fp16

    convert_weights<<<(D * 2 * D + 16 * D + 255) / 256, 256, 0, stream>>>(
        W1, W2, W1h, W2h);

    int groupsU = (n_users + 127) / 128;
    int groupsV = (n_movies + 127) / 128;
    precompute_uv<<<groupsU + groupsV, 256, 0, stream>>>(
        ufeat, ifeat, W1h, Ubuf, Vbuf, n_users, n_movies, groupsU);

    int eblocks = (E + 255) / 256;
    edge_mlp<<<eblocks, 256, 0, stream>>>(Ubuf, Vbuf, W2h, src, dst, out, E);
}